// Round 8
// baseline (33214.954 us; speedup 1.0000x reference)
//
#include <hip/hip_runtime.h>
#include <hip/hip_bf16.h>

// Problem sizes (fixed by the reference)
#define SEQ   8192
#define DIN   1024
#define DH    2048
#define DOUT  1024

// ws layout:
//   xw    : SEQ*DH floats (64 MB)
//   hs    : SEQ*DH floats (64 MB)   -- plain data, NO sentinels
//   flags : SEQ*128 bytes (1 MB)    -- flags[t][wg] = 0xFF when WG wg's rows
//                                      of h[t] are visible at MALL scope

// ---------------------------------------------------------------------------
// Zero the flag array (must run every launch; harness doesn't re-poison ws)
// ---------------------------------------------------------------------------
__global__ __launch_bounds__(256) void init_flags_kernel(uint4* __restrict__ p, size_t n4) {
    size_t i = (size_t)blockIdx.x * blockDim.x + threadIdx.x;
    size_t stride = (size_t)gridDim.x * blockDim.x;
    uint4 z = make_uint4(0u, 0u, 0u, 0u);
    for (; i < n4; i += stride) p[i] = z;
}

// ---------------------------------------------------------------------------
// C[m][n] = bias[n] + sum_k A[m][k] * B[n][k]    (A: MxK, B: NxK, C: MxN)
// 64x64 tile, BK=16, 256 threads, 4x4 per-thread accumulators. fp32.
// ---------------------------------------------------------------------------
__global__ __launch_bounds__(256) void gemm_nt_bias(
    const float* __restrict__ A, const float* __restrict__ B,
    const float* __restrict__ bias, float* __restrict__ C,
    int M, int N, int K) {
    __shared__ float As[16][68];
    __shared__ float Bs[16][68];
    const int tid = threadIdx.x;
    const int bm = blockIdx.x * 64;
    const int bn = blockIdx.y * 64;
    const int lr = tid >> 2;
    const int lk = (tid & 3) * 4;
    const int tm = (tid >> 4) * 4;
    const int tn = (tid & 15) * 4;
    float acc[4][4] = {};

    for (int k0 = 0; k0 < K; k0 += 16) {
        const float4 av = *(const float4*)&A[(size_t)(bm + lr) * K + k0 + lk];
        const float4 bv = *(const float4*)&B[(size_t)(bn + lr) * K + k0 + lk];
        As[lk + 0][lr] = av.x; As[lk + 1][lr] = av.y;
        As[lk + 2][lr] = av.z; As[lk + 3][lr] = av.w;
        Bs[lk + 0][lr] = bv.x; Bs[lk + 1][lr] = bv.y;
        Bs[lk + 2][lr] = bv.z; Bs[lk + 3][lr] = bv.w;
        __syncthreads();
#pragma unroll
        for (int k = 0; k < 16; ++k) {
            const float4 a4 = *(const float4*)&As[k][tm];
            const float4 b4 = *(const float4*)&Bs[k][tn];
            const float a[4] = {a4.x, a4.y, a4.z, a4.w};
            const float b[4] = {b4.x, b4.y, b4.z, b4.w};
#pragma unroll
            for (int i = 0; i < 4; ++i)
#pragma unroll
                for (int j = 0; j < 4; ++j)
                    acc[i][j] = fmaf(a[i], b[j], acc[i][j]);
        }
        __syncthreads();
    }

    const float4 bv = *(const float4*)&bias[bn + tn];
#pragma unroll
    for (int i = 0; i < 4; ++i) {
        float4 o;
        o.x = acc[i][0] + bv.x;
        o.y = acc[i][1] + bv.y;
        o.z = acc[i][2] + bv.z;
        o.w = acc[i][3] + bv.w;
        *(float4*)&C[(size_t)(bm + tm + i) * N + bn + tn] = o;
    }
}

// ---------------------------------------------------------------------------
// Persistent recurrence: 128 WGs x 256 threads, one WG per CU. WG b owns rows
// [16b,16b+16) of W_hh in pinned VGPRs (R4 structure, proven correct).
// FLAG/EPOCH protocol (replaces sentinel polling -- R7 post-mortem):
//   producer: store h rows (agent) -> __syncthreads (drains vmcnt, all waves)
//             -> tid0 sets byte flags[t][wg] (agent). Flag is written only
//             after data is MALL-visible.
//   consumer: wave 0 polls the 128B flag block for step t-1 (2 cache lines,
//             sc0 sc1) until all 128 bytes == 0xFF; barrier; then ONE batched
//             sentinel-free 8KB read of h[t-1] (2x dwordx4 sc0 sc1, single
//             vmcnt) -> LDS -> compute. 64x less poll traffic than R4.
// ---------------------------------------------------------------------------
__global__ __attribute__((amdgpu_flat_work_group_size(256, 256),
                          amdgpu_waves_per_eu(1, 1)))
void rnn_recurrence(
    const float* __restrict__ Whh, const float* __restrict__ xw,
    const float* __restrict__ h0, float* __restrict__ hs,
    unsigned char* __restrict__ flags) {
    __shared__ float h_lds[2][DH];
    const int tid = threadIdx.x;
    const int wave = tid >> 6;
    const int lane = tid & 63;
    const int row0 = blockIdx.x * 16 + wave * 4;  // this wave's first row

    // Load this wave's 4x2048 weight slice and PIN it in registers.
    float4 w4[4][8];
#pragma unroll
    for (int r = 0; r < 4; ++r)
#pragma unroll
        for (int j = 0; j < 8; ++j) {
            w4[r][j] = *(const float4*)&Whh[(size_t)(row0 + r) * DH + lane * 4 + 256 * j];
            asm volatile("" : "+v"(w4[r][j].x), "+v"(w4[r][j].y),
                              "+v"(w4[r][j].z), "+v"(w4[r][j].w));
        }

    for (int t = 0; t < SEQ; ++t) {
        const int par = t & 1;
        // prefetch xw for this wave's rows (issues before the poll)
        const float xwv = xw[(size_t)t * DH + row0 + (lane & 3)];

        if (t == 0) {
#pragma unroll
            for (int j = 0; j < 8; ++j)
                h_lds[0][j * 256 + tid] = h0[j * 256 + tid];
        } else {
            // ---- wave 0: poll the 128-byte flag block for step t-1 ----
            if (wave == 0) {
                const unsigned char* fb = flags + (size_t)(t - 1) * 128 + 16 * (lane & 7);
                for (;;) {
                    uint4 f;
                    asm volatile(
                        "global_load_dwordx4 %0, %1, off sc0 sc1\n\t"
                        "s_waitcnt vmcnt(0)"
                        : "=&v"(f) : "v"(fb) : "memory");
                    const bool ok = (f.x == ~0u) & (f.y == ~0u) &
                                    (f.z == ~0u) & (f.w == ~0u);
                    if (__builtin_expect(__all(ok), 1)) break;
                }
            }
            __syncthreads();  // flags set => h[t-1] fully MALL-visible

            // ---- ONE batched sentinel-free 8KB bulk read -> LDS ----
            const float* src = hs + (size_t)(t - 1) * DH;
            const float* a0 = src + 4 * tid;
            const float* a1 = src + 1024 + 4 * tid;
            float4 va, vb;
            asm volatile(
                "global_load_dwordx4 %0, %2, off sc0 sc1\n\t"
                "global_load_dwordx4 %1, %3, off sc0 sc1\n\t"
                "s_waitcnt vmcnt(0)"
                : "=&v"(va), "=&v"(vb)
                : "v"(a0), "v"(a1)
                : "memory");
            *(float4*)&h_lds[par][4 * tid] = va;
            *(float4*)&h_lds[par][1024 + 4 * tid] = vb;
        }
        __syncthreads();  // LDS ready

        // ---- pull h into registers in the compute pattern ----
        float4 h4[8];
#pragma unroll
        for (int j = 0; j < 8; ++j)
            h4[j] = *(const float4*)&h_lds[par][lane * 4 + 256 * j];

        // ---- 4 rows x 32 cols of FMAs per lane ----
        float acc0 = 0.f, acc1 = 0.f, acc2 = 0.f, acc3 = 0.f;
#pragma unroll
        for (int j = 0; j < 8; ++j) {
            const float4 hv = h4[j];
            acc0 = fmaf(w4[0][j].x, hv.x, acc0); acc0 = fmaf(w4[0][j].y, hv.y, acc0);
            acc0 = fmaf(w4[0][j].z, hv.z, acc0); acc0 = fmaf(w4[0][j].w, hv.w, acc0);
            acc1 = fmaf(w4[1][j].x, hv.x, acc1); acc1 = fmaf(w4[1][j].y, hv.y, acc1);
            acc1 = fmaf(w4[1][j].z, hv.z, acc1); acc1 = fmaf(w4[1][j].w, hv.w, acc1);
            acc2 = fmaf(w4[2][j].x, hv.x, acc2); acc2 = fmaf(w4[2][j].y, hv.y, acc2);
            acc2 = fmaf(w4[2][j].z, hv.z, acc2); acc2 = fmaf(w4[2][j].w, hv.w, acc2);
            acc3 = fmaf(w4[3][j].x, hv.x, acc3); acc3 = fmaf(w4[3][j].y, hv.y, acc3);
            acc3 = fmaf(w4[3][j].z, hv.z, acc3); acc3 = fmaf(w4[3][j].w, hv.w, acc3);
        }

        // ---- select-merge butterfly: 7 shuffles, lane l ends with row (l&3) ----
        float a01 = (lane & 1) ? acc1 : acc0;
        float b01 = (lane & 1) ? acc0 : acc1;
        a01 += __shfl_xor(b01, 1);
        float a23 = (lane & 1) ? acc3 : acc2;
        float b23 = (lane & 1) ? acc2 : acc3;
        a23 += __shfl_xor(b23, 1);
        float a = (lane & 2) ? a23 : a01;
        float b = (lane & 2) ? a01 : a23;
        a += __shfl_xor(b, 2);
        a += __shfl_xor(a, 4);
        a += __shfl_xor(a, 8);
        a += __shfl_xor(a, 16);
        a += __shfl_xor(a, 32);

        // ---- tanh + agent-visible store of this wave's 4 rows ----
        if (lane < 4) {
            const float hval = tanhf(a + xwv);
            __hip_atomic_store((unsigned*)(hs + (size_t)t * DH + row0 + lane),
                               __float_as_uint(hval),
                               __ATOMIC_RELAXED, __HIP_MEMORY_SCOPE_AGENT);
        }

        // ---- WG-wide drain (compiler emits vmcnt(0) before s_barrier),
        //      then publish this WG's flag for step t ----
        __syncthreads();
        if (tid == 0)
            __hip_atomic_store(flags + (size_t)t * 128 + blockIdx.x,
                               (unsigned char)0xFF,
                               __ATOMIC_RELAXED, __HIP_MEMORY_SCOPE_AGENT);
    }
}

// ---------------------------------------------------------------------------
__global__ __launch_bounds__(256) void copy_hfinal(const float* __restrict__ hs,
                                                   float* __restrict__ out) {
    const int i = blockIdx.x * 256 + threadIdx.x;
    out[i] = hs[(size_t)(SEQ - 1) * DH + i];
}

// ---------------------------------------------------------------------------
extern "C" void kernel_launch(void* const* d_in, const int* in_sizes, int n_in,
                              void* d_out, int out_size, void* d_ws, size_t ws_size,
                              hipStream_t stream) {
    (void)in_sizes; (void)n_in; (void)out_size; (void)ws_size;
    const float* x_seq  = (const float*)d_in[0];  // (SEQ, DIN)
    const float* h0     = (const float*)d_in[1];  // (DH,)
    const float* W_ih   = (const float*)d_in[2];  // (DH, DIN)
    const float* W_hh   = (const float*)d_in[3];  // (DH, DH)
    const float* b_h    = (const float*)d_in[4];  // (DH,)
    const float* W_ho_w = (const float*)d_in[5];  // (DOUT, DH)
    const float* W_ho_b = (const float*)d_in[6];  // (DOUT,)
    float* out = (float*)d_out;                   // (SEQ*DOUT) then (DH,)

    float* xw = (float*)d_ws;                         // 64 MB
    float* hs = xw + (size_t)SEQ * DH;                // 64 MB
    unsigned char* flags = (unsigned char*)(hs + (size_t)SEQ * DH);  // 1 MB

    // 1) zero flags (the only state that must be reset each launch)
    init_flags_kernel<<<256, 256, 0, stream>>>((uint4*)flags,
                                               (size_t)SEQ * 128 / 16);

    // 2) xw = x_seq @ W_ih.T + b_h
    gemm_nt_bias<<<dim3(SEQ / 64, DH / 64), 256, 0, stream>>>(
        x_seq, W_ih, b_h, xw, SEQ, DH, DIN);

    // 3) sequential recurrence (persistent dataflow kernel, flag protocol)
    rnn_recurrence<<<DH / 16, 256, 0, stream>>>(W_hh, xw, h0, hs, flags);

    // 4) out = hs @ W_ho_w.T + W_ho_b
    gemm_nt_bias<<<dim3(SEQ / 64, DOUT / 64), 256, 0, stream>>>(
        hs, W_ho_w, W_ho_b, out, SEQ, DOUT, DH);

    // 5) h_final
    copy_hfinal<<<DH / 256, 256, 0, stream>>>(hs, out + (size_t)SEQ * DOUT);
}

// Round 9
// 22943.335 us; speedup vs baseline: 1.4477x; 1.4477x over previous
//
#include <hip/hip_runtime.h>
#include <hip/hip_bf16.h>

// Problem sizes (fixed by the reference)
#define SEQ   8192
#define DIN   1024
#define DH    2048
#define DOUT  1024

#define SENT 0x7fc0deadu  // quiet-NaN payload; tanh output can never equal this

// ---------------------------------------------------------------------------
// Fill hs with sentinel (must run every launch: harness does not re-poison ws)
// ---------------------------------------------------------------------------
__global__ __launch_bounds__(256) void fill_sent_kernel(uint4* __restrict__ p, size_t n4) {
    size_t i = (size_t)blockIdx.x * blockDim.x + threadIdx.x;
    size_t stride = (size_t)gridDim.x * blockDim.x;
    uint4 v = make_uint4(SENT, SENT, SENT, SENT);
    for (; i < n4; i += stride) p[i] = v;
}

// ---------------------------------------------------------------------------
// C[m][n] = bias[n] + sum_k A[m][k] * B[n][k]    (A: MxK, B: NxK, C: MxN)
// 64x64 tile, BK=16, 256 threads, 4x4 per-thread accumulators. fp32.
// ---------------------------------------------------------------------------
__global__ __launch_bounds__(256) void gemm_nt_bias(
    const float* __restrict__ A, const float* __restrict__ B,
    const float* __restrict__ bias, float* __restrict__ C,
    int M, int N, int K) {
    __shared__ float As[16][68];
    __shared__ float Bs[16][68];
    const int tid = threadIdx.x;
    const int bm = blockIdx.x * 64;
    const int bn = blockIdx.y * 64;
    const int lr = tid >> 2;
    const int lk = (tid & 3) * 4;
    const int tm = (tid >> 4) * 4;
    const int tn = (tid & 15) * 4;
    float acc[4][4] = {};

    for (int k0 = 0; k0 < K; k0 += 16) {
        const float4 av = *(const float4*)&A[(size_t)(bm + lr) * K + k0 + lk];
        const float4 bv = *(const float4*)&B[(size_t)(bn + lr) * K + k0 + lk];
        As[lk + 0][lr] = av.x; As[lk + 1][lr] = av.y;
        As[lk + 2][lr] = av.z; As[lk + 3][lr] = av.w;
        Bs[lk + 0][lr] = bv.x; Bs[lk + 1][lr] = bv.y;
        Bs[lk + 2][lr] = bv.z; Bs[lk + 3][lr] = bv.w;
        __syncthreads();
#pragma unroll
        for (int k = 0; k < 16; ++k) {
            const float4 a4 = *(const float4*)&As[k][tm];
            const float4 b4 = *(const float4*)&Bs[k][tn];
            const float a[4] = {a4.x, a4.y, a4.z, a4.w};
            const float b[4] = {b4.x, b4.y, b4.z, b4.w};
#pragma unroll
            for (int i = 0; i < 4; ++i)
#pragma unroll
                for (int j = 0; j < 4; ++j)
                    acc[i][j] = fmaf(a[i], b[j], acc[i][j]);
        }
        __syncthreads();
    }

    const float4 bv = *(const float4*)&bias[bn + tn];
#pragma unroll
    for (int i = 0; i < 4; ++i) {
        float4 o;
        o.x = acc[i][0] + bv.x;
        o.y = acc[i][1] + bv.y;
        o.z = acc[i][2] + bv.z;
        o.w = acc[i][3] + bv.w;
        *(float4*)&C[(size_t)(bm + tm + i) * N + bn + tn] = o;
    }
}

// ---------------------------------------------------------------------------
// Persistent recurrence: 128 WGs x 256 threads (R4 structure, 21.7ms PROVEN).
// ONLY change vs R4: the poll of h[t-1] is the R6-proven asm-batched form --
// two global_load_dwordx4 sc0 sc1 + ONE s_waitcnt per round, data-is-flag --
// replacing 8 scalar __hip_atomic_loads (~0.3us each, serialized; R1/R2/R4/R8
// step times scale linearly with scalar-poll count).
// ---------------------------------------------------------------------------
__global__ __attribute__((amdgpu_flat_work_group_size(256, 256),
                          amdgpu_waves_per_eu(1, 1)))
void rnn_recurrence(
    const float* __restrict__ Whh, const float* __restrict__ xw,
    const float* __restrict__ h0, float* __restrict__ hs) {
    __shared__ float h_lds[2][DH];
    const int tid = threadIdx.x;
    const int wave = tid >> 6;
    const int lane = tid & 63;
    const int row0 = blockIdx.x * 16 + wave * 4;  // this wave's first row

    // Load this wave's 4x2048 weight slice and PIN it in registers.
    float4 w4[4][8];
#pragma unroll
    for (int r = 0; r < 4; ++r)
#pragma unroll
        for (int j = 0; j < 8; ++j) {
            w4[r][j] = *(const float4*)&Whh[(size_t)(row0 + r) * DH + lane * 4 + 256 * j];
            asm volatile("" : "+v"(w4[r][j].x), "+v"(w4[r][j].y),
                              "+v"(w4[r][j].z), "+v"(w4[r][j].w));
        }

    for (int t = 0; t < SEQ; ++t) {
        const int par = t & 1;
        // prefetch xw for this wave's rows (issues before the poll)
        const float xwv = xw[(size_t)t * DH + row0 + (lane & 3)];

        if (t == 0) {
#pragma unroll
            for (int j = 0; j < 8; ++j)
                h_lds[0][j * 256 + tid] = h0[j * 256 + tid];
        } else {
            // ---- asm-batched sentinel poll: 32B/thread, one RT per round ----
            const float* src = hs + (size_t)(t - 1) * DH;
            const float* a0 = src + 4 * tid;          // words [4t, 4t+4)
            const float* a1 = src + 1024 + 4 * tid;   // words [1024+4t, ..)
            float4 va, vb;
            unsigned bad;
            do {
                asm volatile(
                    "global_load_dwordx4 %0, %2, off sc0 sc1\n\t"
                    "global_load_dwordx4 %1, %3, off sc0 sc1\n\t"
                    "s_waitcnt vmcnt(0)"
                    : "=&v"(va), "=&v"(vb)
                    : "v"(a0), "v"(a1)
                    : "memory");
                bad = (__float_as_uint(va.x) == SENT) | (__float_as_uint(va.y) == SENT) |
                      (__float_as_uint(va.z) == SENT) | (__float_as_uint(va.w) == SENT) |
                      (__float_as_uint(vb.x) == SENT) | (__float_as_uint(vb.y) == SENT) |
                      (__float_as_uint(vb.z) == SENT) | (__float_as_uint(vb.w) == SENT);
            } while (__builtin_expect(bad != 0, 0));
            *(float4*)&h_lds[par][4 * tid] = va;
            *(float4*)&h_lds[par][1024 + 4 * tid] = vb;
        }
        __syncthreads();  // single barrier/step (double-buffered LDS)

        // ---- pull h into registers in the compute pattern ----
        float4 h4[8];
#pragma unroll
        for (int j = 0; j < 8; ++j)
            h4[j] = *(const float4*)&h_lds[par][lane * 4 + 256 * j];

        // ---- 4 rows x 32 cols of FMAs per lane ----
        float acc0 = 0.f, acc1 = 0.f, acc2 = 0.f, acc3 = 0.f;
#pragma unroll
        for (int j = 0; j < 8; ++j) {
            const float4 hv = h4[j];
            acc0 = fmaf(w4[0][j].x, hv.x, acc0); acc0 = fmaf(w4[0][j].y, hv.y, acc0);
            acc0 = fmaf(w4[0][j].z, hv.z, acc0); acc0 = fmaf(w4[0][j].w, hv.w, acc0);
            acc1 = fmaf(w4[1][j].x, hv.x, acc1); acc1 = fmaf(w4[1][j].y, hv.y, acc1);
            acc1 = fmaf(w4[1][j].z, hv.z, acc1); acc1 = fmaf(w4[1][j].w, hv.w, acc1);
            acc2 = fmaf(w4[2][j].x, hv.x, acc2); acc2 = fmaf(w4[2][j].y, hv.y, acc2);
            acc2 = fmaf(w4[2][j].z, hv.z, acc2); acc2 = fmaf(w4[2][j].w, hv.w, acc2);
            acc3 = fmaf(w4[3][j].x, hv.x, acc3); acc3 = fmaf(w4[3][j].y, hv.y, acc3);
            acc3 = fmaf(w4[3][j].z, hv.z, acc3); acc3 = fmaf(w4[3][j].w, hv.w, acc3);
        }

        // ---- select-merge butterfly: 7 shuffles, lane l ends with row (l&3) ----
        float a01 = (lane & 1) ? acc1 : acc0;
        float b01 = (lane & 1) ? acc0 : acc1;
        a01 += __shfl_xor(b01, 1);
        float a23 = (lane & 1) ? acc3 : acc2;
        float b23 = (lane & 1) ? acc2 : acc3;
        a23 += __shfl_xor(b23, 1);
        float a = (lane & 2) ? a23 : a01;
        float b = (lane & 2) ? a01 : a23;
        a += __shfl_xor(b, 2);
        a += __shfl_xor(a, 4);
        a += __shfl_xor(a, 8);
        a += __shfl_xor(a, 16);
        a += __shfl_xor(a, 32);

        // ---- tanh + agent-visible store of this wave's 4 rows ----
        if (lane < 4) {
            const float hval = tanhf(a + xwv);
            __hip_atomic_store((unsigned*)(hs + (size_t)t * DH + row0 + lane),
                               __float_as_uint(hval),
                               __ATOMIC_RELAXED, __HIP_MEMORY_SCOPE_AGENT);
        }
    }
}

// ---------------------------------------------------------------------------
__global__ __launch_bounds__(256) void copy_hfinal(const float* __restrict__ hs,
                                                   float* __restrict__ out) {
    const int i = blockIdx.x * 256 + threadIdx.x;
    out[i] = hs[(size_t)(SEQ - 1) * DH + i];
}

// ---------------------------------------------------------------------------
extern "C" void kernel_launch(void* const* d_in, const int* in_sizes, int n_in,
                              void* d_out, int out_size, void* d_ws, size_t ws_size,
                              hipStream_t stream) {
    (void)in_sizes; (void)n_in; (void)out_size; (void)ws_size;
    const float* x_seq  = (const float*)d_in[0];  // (SEQ, DIN)
    const float* h0     = (const float*)d_in[1];  // (DH,)
    const float* W_ih   = (const float*)d_in[2];  // (DH, DIN)
    const float* W_hh   = (const float*)d_in[3];  // (DH, DH)
    const float* b_h    = (const float*)d_in[4];  // (DH,)
    const float* W_ho_w = (const float*)d_in[5];  // (DOUT, DH)
    const float* W_ho_b = (const float*)d_in[6];  // (DOUT,)
    float* out = (float*)d_out;                   // (SEQ*DOUT) then (DH,)

    float* xw = (float*)d_ws;                     // SEQ*DH fp32 = 64 MB
    float* hs = xw + (size_t)SEQ * DH;            // SEQ*DH fp32 = 64 MB

    // 1) sentinel-fill hs (dataflow flags)
    fill_sent_kernel<<<2048, 256, 0, stream>>>((uint4*)hs, (size_t)SEQ * DH / 4);

    // 2) xw = x_seq @ W_ih.T + b_h
    gemm_nt_bias<<<dim3(SEQ / 64, DH / 64), 256, 0, stream>>>(
        x_seq, W_ih, b_h, xw, SEQ, DH, DIN);

    // 3) sequential recurrence (persistent dataflow kernel)
    rnn_recurrence<<<DH / 16, 256, 0, stream>>>(W_hh, xw, h0, hs);

    // 4) out = hs @ W_ho_w.T + W_ho_b
    gemm_nt_bias<<<dim3(SEQ / 64, DOUT / 64), 256, 0, stream>>>(
        hs, W_ho_w, W_ho_b, out, SEQ, DOUT, DH);

    // 5) h_final
    copy_hfinal<<<DH / 256, 256, 0, stream>>>(hs, out + (size_t)SEQ * DOUT);
}

// Round 10
// 16463.695 us; speedup vs baseline: 2.0175x; 1.3936x over previous
//
#include <hip/hip_runtime.h>
#include <hip/hip_bf16.h>

// Problem sizes (fixed by the reference)
#define SEQ   8192
#define DIN   1024
#define DH    2048
#define DOUT  1024

#define SENT 0x7fc0deadu  // quiet-NaN payload; tanh output can never equal this

// ---------------------------------------------------------------------------
// Fill hs with sentinel (must run every launch: harness does not re-poison ws)
// ---------------------------------------------------------------------------
__global__ __launch_bounds__(256) void fill_sent_kernel(uint4* __restrict__ p, size_t n4) {
    size_t i = (size_t)blockIdx.x * blockDim.x + threadIdx.x;
    size_t stride = (size_t)gridDim.x * blockDim.x;
    uint4 v = make_uint4(SENT, SENT, SENT, SENT);
    for (; i < n4; i += stride) p[i] = v;
}

// ---------------------------------------------------------------------------
// C[m][n] = bias[n] + sum_k A[m][k] * B[n][k]    (A: MxK, B: NxK, C: MxN)
// 64x64 tile, BK=16, 256 threads, 4x4 per-thread accumulators. fp32.
// ---------------------------------------------------------------------------
__global__ __launch_bounds__(256) void gemm_nt_bias(
    const float* __restrict__ A, const float* __restrict__ B,
    const float* __restrict__ bias, float* __restrict__ C,
    int M, int N, int K) {
    __shared__ float As[16][68];
    __shared__ float Bs[16][68];
    const int tid = threadIdx.x;
    const int bm = blockIdx.x * 64;
    const int bn = blockIdx.y * 64;
    const int lr = tid >> 2;
    const int lk = (tid & 3) * 4;
    const int tm = (tid >> 4) * 4;
    const int tn = (tid & 15) * 4;
    float acc[4][4] = {};

    for (int k0 = 0; k0 < K; k0 += 16) {
        const float4 av = *(const float4*)&A[(size_t)(bm + lr) * K + k0 + lk];
        const float4 bv = *(const float4*)&B[(size_t)(bn + lr) * K + k0 + lk];
        As[lk + 0][lr] = av.x; As[lk + 1][lr] = av.y;
        As[lk + 2][lr] = av.z; As[lk + 3][lr] = av.w;
        Bs[lk + 0][lr] = bv.x; Bs[lk + 1][lr] = bv.y;
        Bs[lk + 2][lr] = bv.z; Bs[lk + 3][lr] = bv.w;
        __syncthreads();
#pragma unroll
        for (int k = 0; k < 16; ++k) {
            const float4 a4 = *(const float4*)&As[k][tm];
            const float4 b4 = *(const float4*)&Bs[k][tn];
            const float a[4] = {a4.x, a4.y, a4.z, a4.w};
            const float b[4] = {b4.x, b4.y, b4.z, b4.w};
#pragma unroll
            for (int i = 0; i < 4; ++i)
#pragma unroll
                for (int j = 0; j < 4; ++j)
                    acc[i][j] = fmaf(a[i], b[j], acc[i][j]);
        }
        __syncthreads();
    }

    const float4 bv = *(const float4*)&bias[bn + tn];
#pragma unroll
    for (int i = 0; i < 4; ++i) {
        float4 o;
        o.x = acc[i][0] + bv.x;
        o.y = acc[i][1] + bv.y;
        o.z = acc[i][2] + bv.z;
        o.w = acc[i][3] + bv.w;
        *(float4*)&C[(size_t)(bm + tm + i) * N + bn + tn] = o;
    }
}

// ---------------------------------------------------------------------------
// Persistent recurrence: 128 WGs x 256 threads (R4/R9 structure).
// ONLY change vs R9: COALESCED LINE PUBLISH. A WG's 16 output rows are one
// 64B cache line of hs[t]; R9 wrote them as 16 scalar atomic stores from 4
// different waves -> partial-line dribble at MALL (WRITE_SIZE showed 2x
// amplification), consumers see part-sentinel lines -> extra poll rounds.
// Now: gather 16 values in LDS, barrier, wave 0 lanes 0-15 publish the
// whole line with ONE coalesced 16-lane store.
// ---------------------------------------------------------------------------
__global__ __attribute__((amdgpu_flat_work_group_size(256, 256),
                          amdgpu_waves_per_eu(1, 1)))
void rnn_recurrence(
    const float* __restrict__ Whh, const float* __restrict__ xw,
    const float* __restrict__ h0, float* __restrict__ hs) {
    __shared__ float h_lds[2][DH];
    __shared__ float h_out[16];
    const int tid = threadIdx.x;
    const int wave = tid >> 6;
    const int lane = tid & 63;
    const int row0 = blockIdx.x * 16 + wave * 4;  // this wave's first row

    // Load this wave's 4x2048 weight slice and PIN it in registers.
    float4 w4[4][8];
#pragma unroll
    for (int r = 0; r < 4; ++r)
#pragma unroll
        for (int j = 0; j < 8; ++j) {
            w4[r][j] = *(const float4*)&Whh[(size_t)(row0 + r) * DH + lane * 4 + 256 * j];
            asm volatile("" : "+v"(w4[r][j].x), "+v"(w4[r][j].y),
                              "+v"(w4[r][j].z), "+v"(w4[r][j].w));
        }

    for (int t = 0; t < SEQ; ++t) {
        const int par = t & 1;
        // prefetch xw for this wave's rows (issues before the poll)
        const float xwv = xw[(size_t)t * DH + row0 + (lane & 3)];

        if (t == 0) {
#pragma unroll
            for (int j = 0; j < 8; ++j)
                h_lds[0][j * 256 + tid] = h0[j * 256 + tid];
        } else {
            // ---- asm-batched sentinel poll: 32B/thread, one RT per round ----
            const float* src = hs + (size_t)(t - 1) * DH;
            const float* a0 = src + 4 * tid;          // words [4t, 4t+4)
            const float* a1 = src + 1024 + 4 * tid;   // words [1024+4t, ..)
            float4 va, vb;
            unsigned bad;
            do {
                asm volatile(
                    "global_load_dwordx4 %0, %2, off sc0 sc1\n\t"
                    "global_load_dwordx4 %1, %3, off sc0 sc1\n\t"
                    "s_waitcnt vmcnt(0)"
                    : "=&v"(va), "=&v"(vb)
                    : "v"(a0), "v"(a1)
                    : "memory");
                bad = (__float_as_uint(va.x) == SENT) | (__float_as_uint(va.y) == SENT) |
                      (__float_as_uint(va.z) == SENT) | (__float_as_uint(va.w) == SENT) |
                      (__float_as_uint(vb.x) == SENT) | (__float_as_uint(vb.y) == SENT) |
                      (__float_as_uint(vb.z) == SENT) | (__float_as_uint(vb.w) == SENT);
            } while (__builtin_expect(bad != 0, 0));
            *(float4*)&h_lds[par][4 * tid] = va;
            *(float4*)&h_lds[par][1024 + 4 * tid] = vb;
        }
        __syncthreads();  // h[t-1] staged in LDS

        // ---- pull h into registers in the compute pattern ----
        float4 h4[8];
#pragma unroll
        for (int j = 0; j < 8; ++j)
            h4[j] = *(const float4*)&h_lds[par][lane * 4 + 256 * j];

        // ---- 4 rows x 32 cols of FMAs per lane ----
        float acc0 = 0.f, acc1 = 0.f, acc2 = 0.f, acc3 = 0.f;
#pragma unroll
        for (int j = 0; j < 8; ++j) {
            const float4 hv = h4[j];
            acc0 = fmaf(w4[0][j].x, hv.x, acc0); acc0 = fmaf(w4[0][j].y, hv.y, acc0);
            acc0 = fmaf(w4[0][j].z, hv.z, acc0); acc0 = fmaf(w4[0][j].w, hv.w, acc0);
            acc1 = fmaf(w4[1][j].x, hv.x, acc1); acc1 = fmaf(w4[1][j].y, hv.y, acc1);
            acc1 = fmaf(w4[1][j].z, hv.z, acc1); acc1 = fmaf(w4[1][j].w, hv.w, acc1);
            acc2 = fmaf(w4[2][j].x, hv.x, acc2); acc2 = fmaf(w4[2][j].y, hv.y, acc2);
            acc2 = fmaf(w4[2][j].z, hv.z, acc2); acc2 = fmaf(w4[2][j].w, hv.w, acc2);
            acc3 = fmaf(w4[3][j].x, hv.x, acc3); acc3 = fmaf(w4[3][j].y, hv.y, acc3);
            acc3 = fmaf(w4[3][j].z, hv.z, acc3); acc3 = fmaf(w4[3][j].w, hv.w, acc3);
        }

        // ---- select-merge butterfly: 7 shuffles, lane l ends with row (l&3) ----
        float a01 = (lane & 1) ? acc1 : acc0;
        float b01 = (lane & 1) ? acc0 : acc1;
        a01 += __shfl_xor(b01, 1);
        float a23 = (lane & 1) ? acc3 : acc2;
        float b23 = (lane & 1) ? acc2 : acc3;
        a23 += __shfl_xor(b23, 1);
        float a = (lane & 2) ? a23 : a01;
        float b = (lane & 2) ? a01 : a23;
        a += __shfl_xor(b, 2);
        a += __shfl_xor(a, 4);
        a += __shfl_xor(a, 8);
        a += __shfl_xor(a, 16);
        a += __shfl_xor(a, 32);

        // ---- tanh, stage into LDS, then ONE coalesced 64B line publish ----
        if (lane < 4)
            h_out[wave * 4 + lane] = tanhf(a + xwv);
        __syncthreads();  // all 16 values staged
        if (tid < 16)
            __hip_atomic_store((unsigned*)(hs + (size_t)t * DH + blockIdx.x * 16 + tid),
                               __float_as_uint(h_out[tid]),
                               __ATOMIC_RELAXED, __HIP_MEMORY_SCOPE_AGENT);
    }
}

// ---------------------------------------------------------------------------
__global__ __launch_bounds__(256) void copy_hfinal(const float* __restrict__ hs,
                                                   float* __restrict__ out) {
    const int i = blockIdx.x * 256 + threadIdx.x;
    out[i] = hs[(size_t)(SEQ - 1) * DH + i];
}

// ---------------------------------------------------------------------------
extern "C" void kernel_launch(void* const* d_in, const int* in_sizes, int n_in,
                              void* d_out, int out_size, void* d_ws, size_t ws_size,
                              hipStream_t stream) {
    (void)in_sizes; (void)n_in; (void)out_size; (void)ws_size;
    const float* x_seq  = (const float*)d_in[0];  // (SEQ, DIN)
    const float* h0     = (const float*)d_in[1];  // (DH,)
    const float* W_ih   = (const float*)d_in[2];  // (DH, DIN)
    const float* W_hh   = (const float*)d_in[3];  // (DH, DH)
    const float* b_h    = (const float*)d_in[4];  // (DH,)
    const float* W_ho_w = (const float*)d_in[5];  // (DOUT, DH)
    const float* W_ho_b = (const float*)d_in[6];  // (DOUT,)
    float* out = (float*)d_out;                   // (SEQ*DOUT) then (DH,)

    float* xw = (float*)d_ws;                     // SEQ*DH fp32 = 64 MB
    float* hs = xw + (size_t)SEQ * DH;            // SEQ*DH fp32 = 64 MB

    // 1) sentinel-fill hs (dataflow flags)
    fill_sent_kernel<<<2048, 256, 0, stream>>>((uint4*)hs, (size_t)SEQ * DH / 4);

    // 2) xw = x_seq @ W_ih.T + b_h
    gemm_nt_bias<<<dim3(SEQ / 64, DH / 64), 256, 0, stream>>>(
        x_seq, W_ih, b_h, xw, SEQ, DH, DIN);

    // 3) sequential recurrence (persistent dataflow kernel)
    rnn_recurrence<<<DH / 16, 256, 0, stream>>>(W_hh, xw, h0, hs);

    // 4) out = hs @ W_ho_w.T + W_ho_b
    gemm_nt_bias<<<dim3(SEQ / 64, DOUT / 64), 256, 0, stream>>>(
        hs, W_ho_w, W_ho_b, out, SEQ, DOUT, DH);

    // 5) h_final
    copy_hfinal<<<DH / 256, 256, 0, stream>>>(hs, out + (size_t)SEQ * DOUT);
}